// Round 3
// baseline (175.851 us; speedup 1.0000x reference)
//
#include <hip/hip_runtime.h>
#include <math.h>

// x: (512, 3, 32, 32) fp32
// layer1: C=3 -> F=32, R=16, 3x3  -> (512,32,30,30)
// layer2: C=32 -> F=32, R=16, 3x3 -> (512,32,28,28)
// classifier: 25088 -> 10, then log_softmax
//
// Algebraic fusion (h1, h2 never materialized):
//   M[r1][r2]      = sum_f l1_f0[f][r1] * l2_f3[f][r2]            (16x16)
//   Wc2[n][r2][q]  = sum_f l2_f0[f][r2] * W_cls[n][f*784+q]       (10x16x784)
//
// Numerics: factors are scaled by 0.1 -> logits ~2e-5, outputs ~ -ln(10).
// bf16 (truncated) intermediates introduce absolute output error <1e-6,
// threshold is 4.6e-2. LDS ping-pong in bf16: 32 KB + 28.8 KB + ~3 KB
// tables = ~65 KB < 80 KB -> 2 blocks/CU with VGPR<=64 (launch_bounds 1024,8).

#define NT 1024

__device__ __forceinline__ float bflo(unsigned int u) {
    unsigned int v = u << 16; float f; __builtin_memcpy(&f, &v, 4); return f;
}
__device__ __forceinline__ float bfhi(unsigned int u) {
    unsigned int v = u & 0xffff0000u; float f; __builtin_memcpy(&f, &v, 4); return f;
}
__device__ __forceinline__ unsigned int pack2bf(float lo, float hi) {
    unsigned int a, b;
    __builtin_memcpy(&a, &lo, 4); __builtin_memcpy(&b, &hi, 4);
    return (a >> 16) | (b & 0xffff0000u);
}

__global__ void precomp_kernel(const float* __restrict__ l1_f0,
                               const float* __restrict__ l2_f0,
                               const float* __restrict__ l2_f3,
                               const float* __restrict__ Wcls,
                               float* __restrict__ Wc2,
                               float* __restrict__ Mm) {
    int id = blockIdx.x * blockDim.x + threadIdx.x;
    if (id < 7840) {                      // 10 classes x 784 pixels
        int n = id / 784;
        int pix = id - n * 784;
        const float* wrow = &Wcls[n * 25088 + pix];
        float acc[16];
#pragma unroll
        for (int r2 = 0; r2 < 16; ++r2) acc[r2] = 0.f;
#pragma unroll
        for (int f = 0; f < 32; ++f) {
            float wv = wrow[f * 784];
#pragma unroll
            for (int r2 = 0; r2 < 16; ++r2)
                acc[r2] += l2_f0[f * 16 + r2] * wv;
        }
#pragma unroll
        for (int r2 = 0; r2 < 16; ++r2)
            Wc2[(n * 16 + r2) * 784 + pix] = acc[r2];
    }
    if (id < 256) {
        int r1 = id >> 4, r2 = id & 15;
        float acc = 0.f;
#pragma unroll
        for (int f = 0; f < 32; ++f)
            acc += l1_f0[f * 16 + r1] * l2_f3[f * 16 + r2];
        Mm[id] = acc;
    }
}

__global__ __launch_bounds__(NT, 8) void fused_kernel(
    const float* __restrict__ x,
    const float* __restrict__ l1_f1, const float* __restrict__ l1_f2,
    const float* __restrict__ l1_f3,
    const float* __restrict__ l2_f1, const float* __restrict__ l2_f2,
    const float* __restrict__ Wc2, const float* __restrict__ Mm,
    const float* __restrict__ b_cls,
    float* __restrict__ out) {
    // bf16 ping-pong: sA holds s1 (16x1024) then u (16x900);
    //                 sB holds t1 (16x900) then t2 (16x784).
    __shared__ alignas(16) unsigned short sA[16 * 1024];  // 32 KB
    __shared__ alignas(16) unsigned short sB[16 * 900];   // 28.8 KB
    __shared__ float sw1[144];
    __shared__ float sw2[144];
    __shared__ alignas(16) float sM[256];                 // M [r1][r2]
    __shared__ float sred[16 * 10];
    __shared__ float slog[10];

    const int tid = threadIdx.x;
    const int b = blockIdx.x;

    // ---- stage 0: conv weight tables into LDS ----
    if (tid < 144) {
        int r = tid / 9, ij = tid - r * 9;
        int i = ij / 3, j = ij - i * 3;
        sw1[tid] = l1_f1[i * 16 + r] * l1_f2[j * 16 + r];
    }
    if (tid >= 144 && tid < 288) {
        int t = tid - 144;
        int r = t / 9, ij = t - r * 9;
        int i = ij / 3, j = ij - i * 3;
        sw2[t] = l2_f1[i * 16 + r] * l2_f2[j * 16 + r];
    }
    if (tid >= 288 && tid < 544) sM[tid - 288] = Mm[tid - 288];

    // ---- stage 1: s1[r][p] = sum_c x[b][c][p]*l1_f3[c][r]; 2 px/thread ----
    if (tid < 512) {
        const int p = tid * 2;
        float2 x0 = *(const float2*)&x[b * 3072 + p];
        float2 x1 = *(const float2*)&x[b * 3072 + 1024 + p];
        float2 x2 = *(const float2*)&x[b * 3072 + 2048 + p];
        unsigned int* sAw = (unsigned int*)sA;
#pragma unroll
        for (int r = 0; r < 16; ++r) {
            float f0 = l1_f3[r], f1 = l1_f3[16 + r], f2 = l1_f3[32 + r];
            float lo = x0.x * f0 + x1.x * f1 + x2.x * f2;
            float hi = x0.y * f0 + x1.y * f1 + x2.y * f2;
            sAw[r * 512 + tid] = pack2bf(lo, hi);
        }
    }
    __syncthreads();

    // ---- stage 2: t1[r] = conv3x3(s1[r], w1[r]) -> sB[r*900 + row*30 + col]
    // thread -> (r, colpair 0..14, rowquarter 0..3); 2 outputs/step
    if (tid < 960) {
        const int r = tid / 60;
        const int t = tid - r * 60;
        const int q = t / 15;
        const int pr = t - q * 15;
        const int c = 2 * pr;
        const int row0 = q * 8;
        const int nrows = (q == 3) ? 6 : 8;
        const float* wp = &sw1[r * 9];
        const float w0 = wp[0], w1 = wp[1], w2 = wp[2];
        const float w3 = wp[3], w4 = wp[4], w5 = wp[5];
        const float w6 = wp[6], w7 = wp[7], w8 = wp[8];
        const unsigned short* base = &sA[r * 1024 + row0 * 32 + c];
        unsigned int ua0 = *(const unsigned int*)&base[0];
        unsigned int ua1 = *(const unsigned int*)&base[2];
        unsigned int ub0 = *(const unsigned int*)&base[32];
        unsigned int ub1 = *(const unsigned int*)&base[34];
        float a0 = bflo(ua0), a1 = bfhi(ua0), a2 = bflo(ua1), a3 = bfhi(ua1);
        float b0 = bflo(ub0), b1 = bfhi(ub0), b2 = bflo(ub1), b3 = bfhi(ub1);
        unsigned int* op = (unsigned int*)&sB[r * 900 + row0 * 30 + c];
#pragma unroll
        for (int s = 0; s < 8; ++s) {
            if (s < nrows) {
                const unsigned short* rp = base + (s + 2) * 32;
                unsigned int uc0 = *(const unsigned int*)&rp[0];
                unsigned int uc1 = *(const unsigned int*)&rp[2];
                float c0 = bflo(uc0), c1 = bfhi(uc0), c2 = bflo(uc1), c3 = bfhi(uc1);
                float o0 = w0 * a0 + w1 * a1 + w2 * a2
                         + w3 * b0 + w4 * b1 + w5 * b2
                         + w6 * c0 + w7 * c1 + w8 * c2;
                float o1 = w0 * a1 + w1 * a2 + w2 * a3
                         + w3 * b1 + w4 * b2 + w5 * b3
                         + w6 * c1 + w7 * c2 + w8 * c3;
                *(unsigned int*)((unsigned short*)op + s * 30) = pack2bf(o0, o1);
                a0 = b0; a1 = b1; a2 = b2; a3 = b3;
                b0 = c0; b1 = c1; b2 = c2; b3 = c3;
            }
        }
    }
    __syncthreads();

    // ---- stage 3: u[r2][p] = sum_r1 t1[r1][p]*M[r1][r2] -> sA (bf16)
    // 4 px x 4 r2 register tile; 900 threads
    if (tid < 900) {
        const int tr = tid & 3;
        const int tp = tid >> 2;
        const int p4 = tp * 4;
        const int r2b = tr * 4;
        float a00 = 0.f, a01 = 0.f, a02 = 0.f, a03 = 0.f;
        float a10 = 0.f, a11 = 0.f, a12 = 0.f, a13 = 0.f;
        float a20 = 0.f, a21 = 0.f, a22 = 0.f, a23 = 0.f;
        float a30 = 0.f, a31 = 0.f, a32 = 0.f, a33 = 0.f;
#pragma unroll
        for (int r1 = 0; r1 < 16; ++r1) {
            uint2 tv = *(const uint2*)&sB[r1 * 900 + p4];
            float t0 = bflo(tv.x), t1 = bfhi(tv.x);
            float t2 = bflo(tv.y), t3 = bfhi(tv.y);
            float4 mv = *(const float4*)&sM[r1 * 16 + r2b];
            a00 += mv.x * t0; a01 += mv.x * t1; a02 += mv.x * t2; a03 += mv.x * t3;
            a10 += mv.y * t0; a11 += mv.y * t1; a12 += mv.y * t2; a13 += mv.y * t3;
            a20 += mv.z * t0; a21 += mv.z * t1; a22 += mv.z * t2; a23 += mv.z * t3;
            a30 += mv.w * t0; a31 += mv.w * t1; a32 += mv.w * t2; a33 += mv.w * t3;
        }
        uint2 o;
        o.x = pack2bf(a00, a01); o.y = pack2bf(a02, a03);
        *(uint2*)&sA[(r2b + 0) * 900 + p4] = o;
        o.x = pack2bf(a10, a11); o.y = pack2bf(a12, a13);
        *(uint2*)&sA[(r2b + 1) * 900 + p4] = o;
        o.x = pack2bf(a20, a21); o.y = pack2bf(a22, a23);
        *(uint2*)&sA[(r2b + 2) * 900 + p4] = o;
        o.x = pack2bf(a30, a31); o.y = pack2bf(a32, a33);
        *(uint2*)&sA[(r2b + 3) * 900 + p4] = o;
    }
    __syncthreads();

    // ---- stage 4: t2[r2] = conv3x3(u[r2], w2[r2]) -> sB[r2*784 + row*28 + col]
    // thread -> (r2, colpair 0..13, rowquarter 0..3); 7 rows each
    if (tid < 896) {
        const int r2 = tid / 56;
        const int t = tid - r2 * 56;
        const int q = t / 14;
        const int pr = t - q * 14;
        const int c = 2 * pr;
        const int row0 = q * 7;
        const float* wp = &sw2[r2 * 9];
        const float w0 = wp[0], w1 = wp[1], w2 = wp[2];
        const float w3 = wp[3], w4 = wp[4], w5 = wp[5];
        const float w6 = wp[6], w7 = wp[7], w8 = wp[8];
        const unsigned short* base = &sA[r2 * 900 + row0 * 30 + c];
        unsigned int ua0 = *(const unsigned int*)&base[0];
        unsigned int ua1 = *(const unsigned int*)&base[2];
        unsigned int ub0 = *(const unsigned int*)&base[30];
        unsigned int ub1 = *(const unsigned int*)&base[32];
        float a0 = bflo(ua0), a1 = bfhi(ua0), a2 = bflo(ua1), a3 = bfhi(ua1);
        float b0 = bflo(ub0), b1 = bfhi(ub0), b2 = bflo(ub1), b3 = bfhi(ub1);
        unsigned short* op = &sB[r2 * 784 + row0 * 28 + c];
#pragma unroll
        for (int s = 0; s < 7; ++s) {
            const unsigned short* rp = base + (s + 2) * 30;
            unsigned int uc0 = *(const unsigned int*)&rp[0];
            unsigned int uc1 = *(const unsigned int*)&rp[2];
            float c0 = bflo(uc0), c1 = bfhi(uc0), c2 = bflo(uc1), c3 = bfhi(uc1);
            float o0 = w0 * a0 + w1 * a1 + w2 * a2
                     + w3 * b0 + w4 * b1 + w5 * b2
                     + w6 * c0 + w7 * c1 + w8 * c2;
            float o1 = w0 * a1 + w1 * a2 + w2 * a3
                     + w3 * b1 + w4 * b2 + w5 * b3
                     + w6 * c1 + w7 * c2 + w8 * c3;
            *(unsigned int*)(op + s * 28) = pack2bf(o0, o1);
            a0 = b0; a1 = b1; a2 = b2; a3 = b3;
            b0 = c0; b1 = c1; b2 = c2; b3 = c3;
        }
    }
    __syncthreads();

    // ---- stage 5: logits[n] = b[n] + sum_e t2[e]*Wc2[n][e]; 8 bf16/chunk ----
    float acc[10];
#pragma unroll
    for (int n = 0; n < 10; ++n) acc[n] = 0.f;
    for (int q = tid; q < 1568; q += NT) {
        uint4 tv = *(const uint4*)&sB[q * 8];
        float t0 = bflo(tv.x), t1 = bfhi(tv.x);
        float t2 = bflo(tv.y), t3 = bfhi(tv.y);
        float t4 = bflo(tv.z), t5 = bfhi(tv.z);
        float t6 = bflo(tv.w), t7 = bfhi(tv.w);
        const float* wp = &Wc2[q * 8];
#pragma unroll
        for (int n = 0; n < 10; ++n) {
            float4 wa = *(const float4*)&wp[n * 12544];
            float4 wb = *(const float4*)&wp[n * 12544 + 4];
            acc[n] += t0 * wa.x + t1 * wa.y + t2 * wa.z + t3 * wa.w
                    + t4 * wb.x + t5 * wb.y + t6 * wb.z + t7 * wb.w;
        }
    }
#pragma unroll
    for (int n = 0; n < 10; ++n) {
        float v = acc[n];
#pragma unroll
        for (int off = 32; off > 0; off >>= 1)
            v += __shfl_down(v, off, 64);
        if ((tid & 63) == 0) sred[(tid >> 6) * 10 + n] = v;
    }
    __syncthreads();
    if (tid < 10) {
        float lg = b_cls[tid];
#pragma unroll
        for (int w = 0; w < 16; ++w) lg += sred[w * 10 + tid];
        slog[tid] = lg;
    }
    __syncthreads();
    if (tid < 10) {
        float m = -1e30f;
#pragma unroll
        for (int n = 0; n < 10; ++n) m = fmaxf(m, slog[n]);
        float s = 0.f;
#pragma unroll
        for (int n = 0; n < 10; ++n) s += expf(slog[n] - m);
        out[b * 10 + tid] = slog[tid] - m - logf(s);
    }
}

extern "C" void kernel_launch(void* const* d_in, const int* in_sizes, int n_in,
                              void* d_out, int out_size, void* d_ws, size_t ws_size,
                              hipStream_t stream) {
    const float* x     = (const float*)d_in[0];
    const float* l1_f0 = (const float*)d_in[1];
    const float* l1_f1 = (const float*)d_in[2];
    const float* l1_f2 = (const float*)d_in[3];
    const float* l1_f3 = (const float*)d_in[4];
    const float* l2_f0 = (const float*)d_in[5];
    const float* l2_f1 = (const float*)d_in[6];
    const float* l2_f2 = (const float*)d_in[7];
    const float* l2_f3 = (const float*)d_in[8];
    const float* Wcls  = (const float*)d_in[9];
    const float* bcls  = (const float*)d_in[10];
    float* out = (float*)d_out;

    float* Wc2 = (float*)d_ws;                 // 10*16*784 floats
    float* Mm  = Wc2 + 10 * 16 * 784;          // 256 floats

    precomp_kernel<<<dim3(31), dim3(256), 0, stream>>>(
        l1_f0, l2_f0, l2_f3, Wcls, Wc2, Mm);
    fused_kernel<<<dim3(512), dim3(NT), 0, stream>>>(
        x, l1_f1, l1_f2, l1_f3, l2_f1, l2_f2, Wc2, Mm, bcls, out);
}

// Round 5
// 111.208 us; speedup vs baseline: 1.5813x; 1.5813x over previous
//
#include <hip/hip_runtime.h>
#include <math.h>

// x: (512, 3, 32, 32) fp32
// layer1: C=3 -> F=32, R=16, 3x3  -> (512,32,30,30)
// layer2: C=32 -> F=32, R=16, 3x3 -> (512,32,28,28)
// classifier: 25088 -> 10, then log_softmax
//
// Algebraic fusion (h1, h2 never materialized):
//   M[r1][r2]      = sum_f l1_f0[f][r1] * l2_f3[f][r2]            (16x16)
//   Wc2[n][r2][q]  = sum_f l2_f0[f][r2] * W_cls[n][f*784+q]       (10x16x784)
//
// Structure: one block per image-HALF (rows split with halo recompute).
// 512 threads, fp32 LDS ~70 KB -> 2 blocks/CU, VGPR cap 128 (no spill).
// Halves meet via atomicAdd of logit partials (exactly 2 commutative
// addends -> deterministic); final tiny kernel adds bias + log_softmax.
//
// Round-5 fix: sM load guard was `tid >= 288 && tid < 544` (NT=1024
// leftover) -> with NT=512, sM[224..255] stayed garbage. Now tid<256.

#define NT 512

__global__ void precomp_kernel(const float* __restrict__ l1_f0,
                               const float* __restrict__ l2_f0,
                               const float* __restrict__ l2_f3,
                               const float* __restrict__ Wcls,
                               float* __restrict__ Wc2,
                               float* __restrict__ Mm,
                               float* __restrict__ Lg) {
    int id = blockIdx.x * blockDim.x + threadIdx.x;
    if (id < 7840) {                      // 10 classes x 784 pixels
        int n = id / 784;
        int pix = id - n * 784;
        const float* wrow = &Wcls[n * 25088 + pix];
        float acc[16];
#pragma unroll
        for (int r2 = 0; r2 < 16; ++r2) acc[r2] = 0.f;
#pragma unroll
        for (int f = 0; f < 32; ++f) {
            float wv = wrow[f * 784];
#pragma unroll
            for (int r2 = 0; r2 < 16; ++r2)
                acc[r2] += l2_f0[f * 16 + r2] * wv;
        }
#pragma unroll
        for (int r2 = 0; r2 < 16; ++r2)
            Wc2[(n * 16 + r2) * 784 + pix] = acc[r2];
    }
    if (id < 256) {
        int r1 = id >> 4, r2 = id & 15;
        float acc = 0.f;
#pragma unroll
        for (int f = 0; f < 32; ++f)
            acc += l1_f0[f * 16 + r1] * l2_f3[f * 16 + r2];
        Mm[id] = acc;
    }
    if (id < 5120) Lg[id] = 0.f;          // zero the logit-partial buffer
}

// Per-half geometry:
//   s1: 18 input rows (r0s = h*14), 16 ranks, row stride 32 -> 16x576
//   t1/u: 16 output rows (global h*14 + i), 30 cols        -> 16x480
//   t2: 14 output rows (global h*14 + j), 28 cols          -> 16x392
__global__ __launch_bounds__(NT, 4) void fused_half_kernel(
    const float* __restrict__ x,
    const float* __restrict__ l1_f1, const float* __restrict__ l1_f2,
    const float* __restrict__ l1_f3,
    const float* __restrict__ l2_f1, const float* __restrict__ l2_f2,
    const float* __restrict__ Wc2, const float* __restrict__ Mm,
    float* __restrict__ Lg) {
    __shared__ alignas(16) float sA[16 * 576];   // s1, then u (16x480)  36.9 KB
    __shared__ alignas(16) float sB[16 * 480];   // t1, then t2 (16x392) 30.7 KB
    __shared__ float sw1[144];
    __shared__ float sw2[144];
    __shared__ alignas(16) float sM[256];        // M [r1][r2]
    __shared__ float sred[8 * 10];

    const int tid = threadIdx.x;
    const int b = blockIdx.x >> 1;
    const int h = blockIdx.x & 1;
    const int r0s = h * 14;                      // first input row of this half

    // ---- stage 0: weight tables ----
    if (tid < 144) {
        int r = tid / 9, ij = tid - r * 9;
        int i = ij / 3, j = ij - i * 3;
        sw1[tid] = l1_f1[i * 16 + r] * l1_f2[j * 16 + r];
    }
    if (tid >= 144 && tid < 288) {
        int t = tid - 144;
        int r = t / 9, ij = t - r * 9;
        int i = ij / 3, j = ij - i * 3;
        sw2[t] = l2_f1[i * 16 + r] * l2_f2[j * 16 + r];
    }
    if (tid < 256) sM[tid] = Mm[tid];            // FIX: was tid in [288,544)

    // ---- stage 1: s1[r][p] = sum_c x[b][c][r0s*32 + p] * l1_f3[c][r] ----
    {
        const int xbase = b * 3072 + r0s * 32;
        {
            const int p = tid;
            float x0 = x[xbase + p];
            float x1 = x[xbase + 1024 + p];
            float x2 = x[xbase + 2048 + p];
#pragma unroll
            for (int r = 0; r < 16; ++r)
                sA[r * 576 + p] = x0 * l1_f3[r] + x1 * l1_f3[16 + r] + x2 * l1_f3[32 + r];
        }
        if (tid < 64) {
            const int p = 512 + tid;
            float x0 = x[xbase + p];
            float x1 = x[xbase + 1024 + p];
            float x2 = x[xbase + 2048 + p];
#pragma unroll
            for (int r = 0; r < 16; ++r)
                sA[r * 576 + p] = x0 * l1_f3[r] + x1 * l1_f3[16 + r] + x2 * l1_f3[32 + r];
        }
    }
    __syncthreads();

    // ---- stage 2: t1[r] = conv3x3(s1[r], w1[r]) -> sB[r*480 + row*30 + col]
    // 480 threads: (r, colpair 0..14, rowgroup 0..1), 8 rows each, 2 outs/step
    if (tid < 480) {
        const int r = tid / 30;
        const int t = tid - r * 30;
        const int q = t / 15;
        const int pr = t - q * 15;
        const int c = 2 * pr;
        const int row0 = q * 8;
        const float* wp = &sw1[r * 9];
        const float w0 = wp[0], w1 = wp[1], w2 = wp[2];
        const float w3 = wp[3], w4 = wp[4], w5 = wp[5];
        const float w6 = wp[6], w7 = wp[7], w8 = wp[8];
        const float* base = &sA[r * 576 + row0 * 32 + c];
        float2 aL = *(const float2*)&base[0];
        float2 aH = *(const float2*)&base[2];
        float2 bL = *(const float2*)&base[32];
        float2 bH = *(const float2*)&base[34];
        float a0 = aL.x, a1 = aL.y, a2 = aH.x, a3 = aH.y;
        float b0 = bL.x, b1 = bL.y, b2 = bH.x, b3 = bH.y;
        float* op = &sB[r * 480 + row0 * 30 + c];
#pragma unroll
        for (int s = 0; s < 8; ++s) {
            const float* rp = base + (s + 2) * 32;
            float2 cL = *(const float2*)&rp[0];
            float2 cH = *(const float2*)&rp[2];
            float c0 = cL.x, c1 = cL.y, c2 = cH.x, c3 = cH.y;
            float o0 = w0 * a0 + w1 * a1 + w2 * a2
                     + w3 * b0 + w4 * b1 + w5 * b2
                     + w6 * c0 + w7 * c1 + w8 * c2;
            float o1 = w0 * a1 + w1 * a2 + w2 * a3
                     + w3 * b1 + w4 * b2 + w5 * b3
                     + w6 * c1 + w7 * c2 + w8 * c3;
            *(float2*)&op[s * 30] = make_float2(o0, o1);
            a0 = b0; a1 = b1; a2 = b2; a3 = b3;
            b0 = c0; b1 = c1; b2 = c2; b3 = c3;
        }
    }
    __syncthreads();

    // ---- stage 3: u[r2][p] = sum_r1 t1[r1][p]*M[r1][r2] -> sA
    // 480 threads: 4 px x 4 r2 register tile
    if (tid < 480) {
        const int tr = tid & 3;
        const int tp = tid >> 2;          // 0..119
        const int p4 = tp * 4;
        const int r2b = tr * 4;
        float a00 = 0.f, a01 = 0.f, a02 = 0.f, a03 = 0.f;
        float a10 = 0.f, a11 = 0.f, a12 = 0.f, a13 = 0.f;
        float a20 = 0.f, a21 = 0.f, a22 = 0.f, a23 = 0.f;
        float a30 = 0.f, a31 = 0.f, a32 = 0.f, a33 = 0.f;
#pragma unroll
        for (int r1 = 0; r1 < 16; ++r1) {
            float4 tv = *(const float4*)&sB[r1 * 480 + p4];
            float4 mv = *(const float4*)&sM[r1 * 16 + r2b];
            a00 += mv.x * tv.x; a01 += mv.x * tv.y; a02 += mv.x * tv.z; a03 += mv.x * tv.w;
            a10 += mv.y * tv.x; a11 += mv.y * tv.y; a12 += mv.y * tv.z; a13 += mv.y * tv.w;
            a20 += mv.z * tv.x; a21 += mv.z * tv.y; a22 += mv.z * tv.z; a23 += mv.z * tv.w;
            a30 += mv.w * tv.x; a31 += mv.w * tv.y; a32 += mv.w * tv.z; a33 += mv.w * tv.w;
        }
        *(float4*)&sA[(r2b + 0) * 480 + p4] = make_float4(a00, a01, a02, a03);
        *(float4*)&sA[(r2b + 1) * 480 + p4] = make_float4(a10, a11, a12, a13);
        *(float4*)&sA[(r2b + 2) * 480 + p4] = make_float4(a20, a21, a22, a23);
        *(float4*)&sA[(r2b + 3) * 480 + p4] = make_float4(a30, a31, a32, a33);
    }
    __syncthreads();

    // ---- stage 4: t2[r2] = conv3x3(u[r2], w2[r2]) -> sB[r2*392 + row*28 + col]
    // 448 threads: (r2, colpair 0..13, rowgroup 0..1), 7 rows each
    if (tid < 448) {
        const int r2 = tid / 28;
        const int t = tid - r2 * 28;
        const int q = t / 14;
        const int pr = t - q * 14;
        const int c = 2 * pr;
        const int row0 = q * 7;
        const float* wp = &sw2[r2 * 9];
        const float w0 = wp[0], w1 = wp[1], w2 = wp[2];
        const float w3 = wp[3], w4 = wp[4], w5 = wp[5];
        const float w6 = wp[6], w7 = wp[7], w8 = wp[8];
        const float* base = &sA[r2 * 480 + row0 * 30 + c];
        float2 aL = *(const float2*)&base[0];
        float2 aH = *(const float2*)&base[2];
        float2 bL = *(const float2*)&base[30];
        float2 bH = *(const float2*)&base[32];
        float a0 = aL.x, a1 = aL.y, a2 = aH.x, a3 = aH.y;
        float b0 = bL.x, b1 = bL.y, b2 = bH.x, b3 = bH.y;
        float* op = &sB[r2 * 392 + row0 * 28 + c];
#pragma unroll
        for (int s = 0; s < 7; ++s) {
            const float* rp = base + (s + 2) * 30;
            float2 cL = *(const float2*)&rp[0];
            float2 cH = *(const float2*)&rp[2];
            float c0 = cL.x, c1 = cL.y, c2 = cH.x, c3 = cH.y;
            float o0 = w0 * a0 + w1 * a1 + w2 * a2
                     + w3 * b0 + w4 * b1 + w5 * b2
                     + w6 * c0 + w7 * c1 + w8 * c2;
            float o1 = w0 * a1 + w1 * a2 + w2 * a3
                     + w3 * b1 + w4 * b2 + w5 * b3
                     + w6 * c1 + w7 * c2 + w8 * c3;
            *(float2*)&op[s * 28] = make_float2(o0, o1);
            a0 = b0; a1 = b1; a2 = b2; a3 = b3;
            b0 = c0; b1 = c1; b2 = c2; b3 = c3;
        }
    }
    __syncthreads();

    // ---- stage 5: partial logits over this half's 6272 t2 elements ----
    float acc[10];
#pragma unroll
    for (int n = 0; n < 10; ++n) acc[n] = 0.f;
    const int hoff = h * 392;
    for (int k = tid; k < 1568; k += NT) {          // 1568 float4 chunks
        const int r2 = k / 98;
        const int rem = k - r2 * 98;
        float4 tv = *(const float4*)&sB[k * 4];
        const float* wp = &Wc2[r2 * 784 + hoff + rem * 4];
#pragma unroll
        for (int n = 0; n < 10; ++n) {
            float4 wv = *(const float4*)&wp[n * 12544];
            acc[n] += tv.x * wv.x + tv.y * wv.y + tv.z * wv.z + tv.w * wv.w;
        }
    }
#pragma unroll
    for (int n = 0; n < 10; ++n) {
        float v = acc[n];
#pragma unroll
        for (int off = 32; off > 0; off >>= 1)
            v += __shfl_down(v, off, 64);
        if ((tid & 63) == 0) sred[(tid >> 6) * 10 + n] = v;
    }
    __syncthreads();
    if (tid < 10) {
        float lg = 0.f;
#pragma unroll
        for (int w = 0; w < 8; ++w) lg += sred[w * 10 + tid];
        atomicAdd(&Lg[b * 10 + tid], lg);
    }
}

__global__ void logsoftmax_kernel(const float* __restrict__ Lg,
                                  const float* __restrict__ b_cls,
                                  float* __restrict__ out) {
    int b = blockIdx.x * blockDim.x + threadIdx.x;
    if (b < 512) {
        float v[10];
        float m = -1e30f;
#pragma unroll
        for (int n = 0; n < 10; ++n) {
            v[n] = Lg[b * 10 + n] + b_cls[n];
            m = fmaxf(m, v[n]);
        }
        float s = 0.f;
#pragma unroll
        for (int n = 0; n < 10; ++n) s += expf(v[n] - m);
        float lse = m + logf(s);
#pragma unroll
        for (int n = 0; n < 10; ++n) out[b * 10 + n] = v[n] - lse;
    }
}

extern "C" void kernel_launch(void* const* d_in, const int* in_sizes, int n_in,
                              void* d_out, int out_size, void* d_ws, size_t ws_size,
                              hipStream_t stream) {
    const float* x     = (const float*)d_in[0];
    const float* l1_f0 = (const float*)d_in[1];
    const float* l1_f1 = (const float*)d_in[2];
    const float* l1_f2 = (const float*)d_in[3];
    const float* l1_f3 = (const float*)d_in[4];
    const float* l2_f0 = (const float*)d_in[5];
    const float* l2_f1 = (const float*)d_in[6];
    const float* l2_f2 = (const float*)d_in[7];
    const float* l2_f3 = (const float*)d_in[8];
    const float* Wcls  = (const float*)d_in[9];
    const float* bcls  = (const float*)d_in[10];
    float* out = (float*)d_out;

    float* Wc2 = (float*)d_ws;                 // 10*16*784 floats
    float* Mm  = Wc2 + 10 * 16 * 784;          // 256 floats
    float* Lg  = Mm + 256;                     // 512*10 logit partials

    precomp_kernel<<<dim3(31), dim3(256), 0, stream>>>(
        l1_f0, l2_f0, l2_f3, Wcls, Wc2, Mm, Lg);
    fused_half_kernel<<<dim3(1024), dim3(NT), 0, stream>>>(
        x, l1_f1, l1_f2, l1_f3, l2_f1, l2_f2, Wc2, Mm, Lg);
    logsoftmax_kernel<<<dim3(2), dim3(256), 0, stream>>>(Lg, bcls, out);
}